// Round 6
// baseline (156.624 us; speedup 1.0000x reference)
//
#include <hip/hip_runtime.h>
#include <math.h>

#define NQ    20000
#define NV    19560
#define NHEAD 4
#define DEPTHD 64

typedef __attribute__((ext_vector_type(8))) short short8;
typedef __attribute__((ext_vector_type(4))) float f32x4;

__device__ __forceinline__ ushort f2bf(float f) {
    uint32_t u = __float_as_uint(f);
    uint32_t r = (u + 0x7FFFu + ((u >> 16) & 1u)) >> 16;
    return (ushort)r;
}
__device__ __forceinline__ float bf_lo(uint32_t d) { return __uint_as_float(d << 16); }
__device__ __forceinline__ float bf_hi(uint32_t d) { return __uint_as_float(d & 0xFFFF0000u); }

// ---------------------------------------------------------------------------
// Weight prep: WvT[n][k]=bf16(Wv[k][n]); WqT[n][k]=bf16(concat cols of Wo|Wod|Wa);
// bq = [bo|bod|ba] fp32.
// ---------------------------------------------------------------------------
__global__ __launch_bounds__(256) void prep_weights(
    const float* __restrict__ Wv, const float* __restrict__ Wo,
    const float* __restrict__ Wod, const float* __restrict__ Wa,
    const float* __restrict__ bo, const float* __restrict__ bod,
    const float* __restrict__ ba,
    ushort* __restrict__ WvT, ushort* __restrict__ WqT, float* __restrict__ bq)
{
    const int b = blockIdx.x;
    const int k = threadIdx.x;
    if (b < 256) {
        WvT[b * 256 + k] = f2bf(Wv[k * 256 + b]);
    } else if (b < 768) {
        const int n = b - 256;
        float w;
        if (n < 256)      w = Wo [k * 256 + n];
        else if (n < 384) w = Wod[k * 128 + (n - 256)];
        else              w = Wa [k * 128 + (n - 384)];
        WqT[n * 256 + k] = f2bf(w);
    } else {
        for (int i = k; i < 512; i += 256) {
            float v;
            if (i < 256)      v = bo[i];
            else if (i < 384) v = bod[i - 256];
            else              v = ba[i - 384];
            bq[i] = v;
        }
    }
}

// ---------------------------------------------------------------------------
// ddist pair table: ddist2[row*64+z] = pack(bf16(d[z]), bf16(d[min(z+1,63)]))
// ---------------------------------------------------------------------------
__global__ __launch_bounds__(256) void prep_ddist(
    const float* __restrict__ ddist, uint32_t* __restrict__ ddist2)
{
    const int idx = blockIdx.x * 256 + threadIdx.x;
    if (idx >= NV * 64) return;
    const int z = idx & 63;
    const float lo = ddist[idx];
    const float hi = ddist[idx + ((z < 63) ? 1 : 0)];
    ddist2[idx] = (uint32_t)f2bf(lo) | ((uint32_t)f2bf(hi) << 16);
}

// ---------------------------------------------------------------------------
// bf16 MFMA GEMM: C = A(fp32,[M][256]) x BT(bf16,[N][256])^T + bias.
// ---------------------------------------------------------------------------
template<bool BF16_OUT>
__global__ __launch_bounds__(256) void gemm_mfma_bf16(
    const float* __restrict__ A, const ushort* __restrict__ BT,
    const float* __restrict__ bias, void* __restrict__ Cout,
    int M, int ldc)
{
    constexpr int K = 256, BK = 32;
    __shared__ ushort Asb[128][40];
    __shared__ ushort Bsb[128][40];

    const int tid  = threadIdx.x;
    const int lane = tid & 63;
    const int wave = tid >> 6;
    const int wm   = wave >> 1;
    const int wn   = wave & 1;
    const int brow = blockIdx.y * 128;
    const int bcol = blockIdx.x * 128;
    const int l15  = lane & 15;
    const int kg   = lane >> 4;

    f32x4 acc[4][4] = {};

    const int rA    = tid >> 1;
    const int partA = tid & 1;

    for (int k0 = 0; k0 < K; k0 += BK) {
        {
            ushort tmp[16];
            if (brow + rA < M) {
                const float* ap = A + (size_t)(brow + rA) * K + k0 + partA * 16;
                #pragma unroll
                for (int i = 0; i < 4; ++i) {
                    float4 v = *reinterpret_cast<const float4*>(ap + i * 4);
                    tmp[i * 4 + 0] = f2bf(v.x);
                    tmp[i * 4 + 1] = f2bf(v.y);
                    tmp[i * 4 + 2] = f2bf(v.z);
                    tmp[i * 4 + 3] = f2bf(v.w);
                }
            } else {
                #pragma unroll
                for (int i = 0; i < 16; ++i) tmp[i] = 0;
            }
            *reinterpret_cast<uint4*>(&Asb[rA][partA * 16 + 0]) = *reinterpret_cast<uint4*>(tmp);
            *reinterpret_cast<uint4*>(&Asb[rA][partA * 16 + 8]) = *reinterpret_cast<uint4*>(tmp + 8);
        }
        #pragma unroll
        for (int i = 0; i < 2; ++i) {
            int f  = tid + i * 256;
            int n  = f >> 2;
            int c8 = (f & 3) * 8;
            uint4 v = *reinterpret_cast<const uint4*>(BT + (size_t)(bcol + n) * K + k0 + c8);
            *reinterpret_cast<uint4*>(&Bsb[n][c8]) = v;
        }
        __syncthreads();

        short8 af[4], bfv[4];
        #pragma unroll
        for (int mf = 0; mf < 4; ++mf)
            af[mf] = *reinterpret_cast<const short8*>(&Asb[wm * 64 + mf * 16 + l15][kg * 8]);
        #pragma unroll
        for (int nf = 0; nf < 4; ++nf)
            bfv[nf] = *reinterpret_cast<const short8*>(&Bsb[wn * 64 + nf * 16 + l15][kg * 8]);
        #pragma unroll
        for (int mf = 0; mf < 4; ++mf)
            #pragma unroll
            for (int nf = 0; nf < 4; ++nf)
                acc[mf][nf] = __builtin_amdgcn_mfma_f32_16x16x32_bf16(af[mf], bfv[nf], acc[mf][nf], 0, 0, 0);
        __syncthreads();
    }

    #pragma unroll
    for (int mf = 0; mf < 4; ++mf) {
        #pragma unroll
        for (int reg = 0; reg < 4; ++reg) {
            int row = brow + wm * 64 + mf * 16 + kg * 4 + reg;
            if (row >= M) continue;
            #pragma unroll
            for (int nf = 0; nf < 4; ++nf) {
                int col = bcol + wn * 64 + nf * 16 + l15;
                float v = acc[mf][nf][reg] + bias[col];
                if (BF16_OUT)
                    ((ushort*)Cout)[(size_t)row * ldc + col] = f2bf(v);
                else
                    ((float*)Cout)[(size_t)row * ldc + col] = v;
            }
        }
    }
}

// ---------------------------------------------------------------------------
// Sampler, 2 queries/block. Wave h = head h; lanes<32 own q0=2b, lanes>=32 own
// q1=2b+1. Phase A: lane j computes point j of its query ONCE (no duplication),
// 4 corner dword pair-gathers, 4 LDS stores. Phase B: all 64 lanes, both
// queries interleaved (32 gathers, 16 acc chains); butterfly; store.
// No __syncthreads: sm[h] is wave-private.
// ---------------------------------------------------------------------------
__global__ __launch_bounds__(256) void deform_sample(
    const float* __restrict__ qproj,    // [NQ,512]
    const ushort* __restrict__ vproj,   // [NV,256] bf16
    const uint32_t* __restrict__ ddist2,// [NV,64] bf16-pair
    const float* __restrict__ refpts,   // [NQ,4,3]
    float* __restrict__ out)            // [NQ,256]
{
    const int b    = blockIdx.x;
    const int h    = threadIdx.x >> 6;
    const int lane = threadIdx.x & 63;
    const int j    = lane & 31;        // point index for this lane's query
    const int qq   = lane >> 5;        // 0: q0, 1: q1
    const int q    = 2 * b + qq;

    __shared__ float2 sm[NHEAD][2][128];

    const float* qrow = qproj + (size_t)q * 512;

    // ---- softmax over this query's 32 logits (within the 32-lane half)
    float logit = qrow[384 + h * 32 + j];
    float m = logit;
    #pragma unroll
    for (int o = 16; o; o >>= 1) m = fmaxf(m, __shfl_xor(m, o));
    float e = __expf(logit - m);
    float s = e;
    #pragma unroll
    for (int o = 16; o; o >>= 1) s += __shfl_xor(s, o);
    const float aw = e / s;

    // ---- coords for point j of query q (computed exactly once)
    const int l  = j >> 3;
    const int p  = j & 7;
    const int zi = p & 3;
    const int Wl = 160 >> l;
    const int Hl = (l == 0) ? 92 : (l == 1) ? 46 : (l == 2) ? 23 : 12;
    const int st = (l == 0) ? 0  : (l == 1) ? 14720 : (l == 2) ? 18400 : 19320;

    const int oidx = (h * 4 + l) * 8 + p;
    const float ox = qrow[oidx * 2 + 0];
    const float oy = qrow[oidx * 2 + 1];
    const float od = qrow[256 + oidx];
    const float rx = refpts[(q * 4 + zi) * 3 + 0];
    const float ry = refpts[(q * 4 + zi) * 3 + 1];
    const float rz = refpts[(q * 4 + zi) * 3 + 2];

    const float x = fmaf(rx, (float)Wl, ox - 0.5f);
    const float y = fmaf(ry, (float)Hl, oy - 0.5f);
    const float z = fmaf(rz, 64.0f,     od - 0.5f);
    const float x0f = floorf(x), y0f = floorf(y), z0f = floorf(z);
    const float fx = x - x0f, fy = y - y0f, fz = z - z0f;
    const int x0 = (int)x0f, y0 = (int)y0f, z0 = (int)z0f;

    // z weights folded for pair-load at z0c: (wlo, whi) on (d[z0c], d[z0c+1])
    const int z0c = min(max(z0, 0), DEPTHD - 1);
    const float wlo = (z0 >= 0 && z0 <= 63) ? (1.f - fz) : ((z0 == -1) ? fz : 0.f);
    const float whi = (z0 >= 0 && z0 <= 62) ? fz : 0.f;

    #pragma unroll
    for (int c = 0; c < 4; ++c) {
        const int   cy = c >> 1, cx = c & 1;
        const int   yi = y0 + cy, xi = x0 + cx;
        const float wy = cy ? fy : (1.f - fy);
        const float wx = cx ? fx : (1.f - fx);
        const bool  valid = (xi >= 0) & (xi < Wl) & (yi >= 0) & (yi < Hl);
        const int   yc = min(max(yi, 0), Hl - 1);
        const int   xc = min(max(xi, 0), Wl - 1);
        const int   row = st + yc * Wl + xc;
        const uint32_t pd = ddist2[row * 64 + z0c];
        const float dscore = wlo * bf_lo(pd) + whi * bf_hi(pd);
        const float coef = valid ? (aw * wx * wy * dscore) : 0.f;
        sm[h][qq][c * 32 + j] = make_float2(coef, __int_as_float(row * 512 + h * 128));
    }
    // no barrier: wave-private LDS buffer (wave-internal lgkmcnt ordering)

    // ---- phase B: both queries, interleaved
    const int g   = lane >> 3;              // corner subgroup 0..7
    const int ch8 = (lane & 7) << 3;        // channel block within head
    const uint32_t chb = (uint32_t)(ch8 << 1);
    const char* vb = (const char*)vproj;
    const float2* s0 = sm[h][0];
    const float2* s1 = sm[h][1];

    float acc0[8] = {}, acc1[8] = {};
    #pragma unroll
    for (int t = 0; t < 16; ++t) {
        const float2 w0 = s0[t * 8 + g];
        const float2 w1 = s1[t * 8 + g];
        const uint4 r0 = *reinterpret_cast<const uint4*>(vb + ((uint32_t)__float_as_int(w0.y) + chb));
        const uint4 r1 = *reinterpret_cast<const uint4*>(vb + ((uint32_t)__float_as_int(w1.y) + chb));
        acc0[0] = fmaf(w0.x, bf_lo(r0.x), acc0[0]);
        acc0[1] = fmaf(w0.x, bf_hi(r0.x), acc0[1]);
        acc0[2] = fmaf(w0.x, bf_lo(r0.y), acc0[2]);
        acc0[3] = fmaf(w0.x, bf_hi(r0.y), acc0[3]);
        acc0[4] = fmaf(w0.x, bf_lo(r0.z), acc0[4]);
        acc0[5] = fmaf(w0.x, bf_hi(r0.z), acc0[5]);
        acc0[6] = fmaf(w0.x, bf_lo(r0.w), acc0[6]);
        acc0[7] = fmaf(w0.x, bf_hi(r0.w), acc0[7]);
        acc1[0] = fmaf(w1.x, bf_lo(r1.x), acc1[0]);
        acc1[1] = fmaf(w1.x, bf_hi(r1.x), acc1[1]);
        acc1[2] = fmaf(w1.x, bf_lo(r1.y), acc1[2]);
        acc1[3] = fmaf(w1.x, bf_hi(r1.y), acc1[3]);
        acc1[4] = fmaf(w1.x, bf_lo(r1.z), acc1[4]);
        acc1[5] = fmaf(w1.x, bf_hi(r1.z), acc1[5]);
        acc1[6] = fmaf(w1.x, bf_lo(r1.w), acc1[6]);
        acc1[7] = fmaf(w1.x, bf_hi(r1.w), acc1[7]);
    }

    #pragma unroll
    for (int o = 8; o <= 32; o <<= 1) {
        #pragma unroll
        for (int k = 0; k < 8; ++k) {
            acc0[k] += __shfl_xor(acc0[k], o);
            acc1[k] += __shfl_xor(acc1[k], o);
        }
    }

    if (g == 0) {
        float* op0 = out + (size_t)(2 * b) * 256 + h * 64 + ch8;
        *reinterpret_cast<float4*>(op0)     = make_float4(acc0[0], acc0[1], acc0[2], acc0[3]);
        *reinterpret_cast<float4*>(op0 + 4) = make_float4(acc0[4], acc0[5], acc0[6], acc0[7]);
        float* op1 = op0 + 256;
        *reinterpret_cast<float4*>(op1)     = make_float4(acc1[0], acc1[1], acc1[2], acc1[3]);
        *reinterpret_cast<float4*>(op1 + 4) = make_float4(acc1[4], acc1[5], acc1[6], acc1[7]);
    }
}

// ---------------------------------------------------------------------------
extern "C" void kernel_launch(void* const* d_in, const int* in_sizes, int n_in,
                              void* d_out, int out_size, void* d_ws, size_t ws_size,
                              hipStream_t stream)
{
    const float* query  = (const float*)d_in[0];
    const float* value  = (const float*)d_in[1];
    const float* ddist  = (const float*)d_in[2];
    const float* refpts = (const float*)d_in[3];
    const float* Wv  = (const float*)d_in[6];
    const float* bv  = (const float*)d_in[7];
    const float* Wo  = (const float*)d_in[8];
    const float* bo  = (const float*)d_in[9];
    const float* Wod = (const float*)d_in[10];
    const float* bod = (const float*)d_in[11];
    const float* Wa  = (const float*)d_in[12];
    const float* ba  = (const float*)d_in[13];
    float* out = (float*)d_out;

    char* ws = (char*)d_ws;
    ushort*   vbuf   = (ushort*)ws;                               // 10,014,720 B
    float*    qbuf   = (float*)(ws + 10014720);                   // 40,960,000 B
    ushort*   WvT    = (ushort*)(ws + 10014720 + 40960000);       // 131,072 B
    ushort*   WqT    = WvT + 256 * 256;                           // 262,144 B
    float*    bq     = (float*)(WqT + 512 * 256);                 // 2,048 B
    uint32_t* ddist2 = (uint32_t*)((char*)bq + 2048);             // 5,007,360 B  (~56.4 MB total)

    dim3 blk(256);

    prep_weights<<<dim3(769), blk, 0, stream>>>(Wv, Wo, Wod, Wa, bo, bod, ba, WvT, WqT, bq);
    prep_ddist<<<dim3((NV * 64 + 255) / 256), blk, 0, stream>>>(ddist, ddist2);

    gemm_mfma_bf16<true><<<dim3(2, (NV + 127) / 128), blk, 0, stream>>>(
        value, WvT, bv, vbuf, NV, 256);

    gemm_mfma_bf16<false><<<dim3(4, (NQ + 127) / 128), blk, 0, stream>>>(
        query, WqT, bq, qbuf, NQ, 512);

    deform_sample<<<dim3(NQ / 2), blk, 0, stream>>>(qbuf, vbuf, ddist2, refpts, out);
}